// Round 3
// baseline (1335.430 us; speedup 1.0000x reference)
//
#include <hip/hip_runtime.h>
#include <hip/hip_bf16.h>

#define DEV __device__ __forceinline__

typedef __attribute__((ext_vector_type(8))) short bhalf8;
typedef __attribute__((ext_vector_type(4))) float floatx4;
typedef unsigned short ushort_t;

constexpr int NB = 16384;   // batch
constexpr int NV = 4096;    // visible
constexpr int NH = 1024;    // hidden
constexpr float MOM = 0.5f;
constexpr float WD  = 1e-4f;
constexpr float LRB = 1e-3f / 16384.0f;

// 256x256 tile, BK=64, 512 threads (8 waves as 2M x 4N)
constexpr int LDS_SHORTS = 65536;            // 128 KiB: [buf2][AB2][kpanel2][row][32]
constexpr size_t LDS_BYTES = 131136;         // + 64B for epilogue reduction

DEV unsigned short f2bf(float f) {
  unsigned u = __builtin_bit_cast(unsigned, f);
  u += 0x7FFFu + ((u >> 16) & 1u);      // RNE
  return (unsigned short)(u >> 16);
}
DEV float bf2f(unsigned short u) {
  unsigned x = ((unsigned)u) << 16;
  return __builtin_bit_cast(float, x);
}
DEV float sigm(float x) { return 1.0f / (1.0f + __expf(-x)); }

DEV void gl16(const ushort_t* g, ushort_t* l) {
  __builtin_amdgcn_global_load_lds(
      (const __attribute__((address_space(1))) void*)g,
      (__attribute__((address_space(3))) void*)l,
      16, 0, 0);
}

// ---------- f32 [R][C] -> bf16 [R][C] and bf16 [C][R] ----------
__global__ void prep_cvt_t(const float* __restrict__ in,
                           ushort_t* __restrict__ obf,
                           ushort_t* __restrict__ oT, int R, int C) {
  __shared__ ushort_t t[64][72];
  const int c0 = blockIdx.x * 64, r0 = blockIdx.y * 64;
  const int tr = threadIdx.x >> 3, tc = (threadIdx.x & 7) * 8;
#pragma unroll
  for (int s = 0; s < 64; s += 32) {
    const float* p = in + (size_t)(r0 + tr + s) * C + c0 + tc;
    floatx4 lo = *(const floatx4*)p, hi = *(const floatx4*)(p + 4);
    bhalf8 r;
    r[0] = (short)f2bf(lo[0]); r[1] = (short)f2bf(lo[1]);
    r[2] = (short)f2bf(lo[2]); r[3] = (short)f2bf(lo[3]);
    r[4] = (short)f2bf(hi[0]); r[5] = (short)f2bf(hi[1]);
    r[6] = (short)f2bf(hi[2]); r[7] = (short)f2bf(hi[3]);
    *(bhalf8*)(obf + (size_t)(r0 + tr + s) * C + c0 + tc) = r;
    *(bhalf8*)&t[tr + s][tc] = r;
  }
  __syncthreads();
#pragma unroll
  for (int s = 0; s < 64; s += 32) {
    bhalf8 v;
#pragma unroll
    for (int j = 0; j < 8; ++j) v[j] = (short)t[tc + j][tr + s];
    *(bhalf8*)(oT + (size_t)(c0 + tr + s) * R + r0 + tc) = v;
  }
}

// ---------- bf16 [R][C] -> bf16 [C][R] ----------
__global__ void transb(const ushort_t* __restrict__ in,
                       ushort_t* __restrict__ out, int R, int C) {
  __shared__ ushort_t t[64][72];
  const int c0 = blockIdx.x * 64, r0 = blockIdx.y * 64;
  const int tr = threadIdx.x >> 3, tc = (threadIdx.x & 7) * 8;
#pragma unroll
  for (int s = 0; s < 64; s += 32) {
    bhalf8 v = *(const bhalf8*)(in + (size_t)(r0 + tr + s) * C + c0 + tc);
    *(bhalf8*)&t[tr + s][tc] = v;
  }
  __syncthreads();
#pragma unroll
  for (int s = 0; s < 64; s += 32) {
    bhalf8 v;
#pragma unroll
    for (int j = 0; j < 8; ++j) v[j] = (short)t[tc + j][tr + s];
    *(bhalf8*)(out + (size_t)(c0 + tr + s) * R + r0 + tc) = v;
  }
}

// ============ 256x256x64 8-phase core ============
// A: [M][ldA] bf16 (tile base Ap = A + m0*ldA + k0), B: [N][ldB] bf16.
// LDS layout per buffer: A: [kpanel2][256 rows][32 cols], swizzled col^16 when row&8.
DEV void core256(const ushort_t* __restrict__ Ap,
                 const ushort_t* __restrict__ Bp,
                 size_t ldA, size_t ldB, int nt,
                 ushort_t* Lp, int wid, int lane,
                 int wr, int wc, floatx4 (&acc)[8][4]) {
  const int lr = lane & 15, kg = lane >> 4;
  const int scol = ((lane & 3) * 8) ^ ((lane & 32) ? 16 : 0);  // pre-swizzled global col
  const ushort_t* pA = Ap + (size_t)(wid * 16 + (lane >> 2)) * ldA + scol;
  const ushort_t* pB = Bp + (size_t)(wid * 16 + (lane >> 2)) * ldB + scol;
  ushort_t* dstA = Lp + wid * 512;
  ushort_t* dstB = Lp + 16384 + wid * 512;
  const int swz = (lr & 8) << 1;                               // read-side swizzle
  const ushort_t* aBase = Lp + (wr * 128 + lr) * 32 + ((kg * 8) ^ swz);
  const ushort_t* bBase = Lp + 16384 + (wc * 64 + lr) * 32 + ((kg * 8) ^ swz);

  auto stage = [&](int buf, int t) {
    const int tb = t * 64;
#pragma unroll
    for (int i = 0; i < 4; ++i) {
      const int lo = buf * 32768 + (i >> 1) * 8192 + (i & 1) * 4096;
      gl16(pA + (size_t)((i & 1) * 128) * ldA + ((i >> 1) * 32 + tb), dstA + lo);
      gl16(pB + (size_t)((i & 1) * 128) * ldB + ((i >> 1) * 32 + tb), dstB + lo);
    }
  };

  stage(0, 0);
  asm volatile("s_waitcnt vmcnt(0)" ::: "memory");
  asm volatile("s_barrier" ::: "memory");

  for (int t = 0; t < nt; ++t) {
    const int curo = (t & 1) * 32768;
#pragma unroll
    for (int q = 0; q < 4; ++q) {
      const int mh = q >> 1, nh = q & 1;
      bhalf8 fa[4][2], fb[2][2];
#pragma unroll
      for (int m2 = 0; m2 < 4; ++m2)
#pragma unroll
        for (int ks = 0; ks < 2; ++ks)
          fa[m2][ks] = *(const bhalf8*)(aBase + curo + ks * 8192 + (mh * 4 + m2) * 512);
#pragma unroll
      for (int n2 = 0; n2 < 2; ++n2)
#pragma unroll
        for (int ks = 0; ks < 2; ++ks)
          fb[n2][ks] = *(const bhalf8*)(bBase + curo + ks * 8192 + (nh * 2 + n2) * 512);
      if (q == 0 && t + 1 < nt) stage((t & 1) ^ 1, t + 1);   // loads fly across 6 barriers
      asm volatile("s_barrier" ::: "memory");
      __builtin_amdgcn_sched_barrier(0);
      __builtin_amdgcn_s_setprio(1);
#pragma unroll
      for (int m2 = 0; m2 < 4; ++m2)
#pragma unroll
        for (int n2 = 0; n2 < 2; ++n2)
#pragma unroll
          for (int ks = 0; ks < 2; ++ks)
            acc[mh * 4 + m2][nh * 2 + n2] = __builtin_amdgcn_mfma_f32_16x16x32_bf16(
                fa[m2][ks], fb[n2][ks], acc[mh * 4 + m2][nh * 2 + n2], 0, 0, 0);
      __builtin_amdgcn_s_setprio(0);
      if (q == 3) asm volatile("s_waitcnt vmcnt(0)" ::: "memory");
      asm volatile("s_barrier" ::: "memory");
    }
  }
}

// ---------------- fused NT GEMM: sigmoid(A @ B^T + bias) + epilogues ----------------
template <int MODE>
__global__ __launch_bounds__(512, 2)
void gemm_fused256(const ushort_t* __restrict__ Ab,
                   const ushort_t* __restrict__ Bb,
                   int N, int K,
                   const float* __restrict__ bias,
                   const float* __restrict__ rand_h0,
                   ushort_t* __restrict__ Pout,
                   float* __restrict__ colsum,
                   const ushort_t* __restrict__ inbf,
                   float* __restrict__ err_accum) {
  extern __shared__ ushort_t Lsh[];
  const int tid = threadIdx.x;
  const int wid = tid >> 6, lane = tid & 63;
  const int wr = wid >> 2, wc = wid & 3;
  const int lr = lane & 15, kg = lane >> 4;

  const int nwg = gridDim.x * gridDim.y;
  const int id = blockIdx.y * gridDim.x + blockIdx.x;
  const int sid = (id & 7) * (nwg >> 3) + (id >> 3);
  const int n0 = (sid % gridDim.x) * 256;
  const int m0 = (sid / gridDim.x) * 256;

  floatx4 acc[8][4] = {};
  core256(Ab + (size_t)m0 * K, Bb + (size_t)n0 * K, K, K, K / 64,
          Lsh, wid, lane, wr, wc, acc);

  if (MODE == 0 || MODE == 2) {
#pragma unroll
    for (int ni = 0; ni < 4; ++ni) {
      const int col = n0 + wc * 64 + ni * 16 + lr;
      const float b = bias[col];
      const float r0 = (MODE == 0) ? rand_h0[col] : 0.0f;
      float cs = 0.0f;
#pragma unroll
      for (int mi = 0; mi < 8; ++mi) {
        const int rowb = m0 + wr * 128 + mi * 16 + kg * 4;
#pragma unroll
        for (int r = 0; r < 4; ++r) {
          const float p = sigm(acc[mi][ni][r] + b);
          cs += p;
          ushort_t ov;
          if (MODE == 0) ov = (p >= r0) ? (ushort_t)0x3F80u : (ushort_t)0u;
          else           ov = f2bf(p);
          Pout[(size_t)(rowb + r) * N + col] = ov;
        }
      }
      cs += __shfl_xor(cs, 16);
      cs += __shfl_xor(cs, 32);
      if (kg == 0) atomicAdd(&colsum[col], cs);
    }
  } else {
    float* ered = (float*)(Lsh + LDS_SHORTS);
    float esum = 0.0f;
#pragma unroll
    for (int ni = 0; ni < 4; ++ni) {
      const int col = n0 + wc * 64 + ni * 16 + lr;
      const float b = bias[col];
      float cs = 0.0f;
#pragma unroll
      for (int mi = 0; mi < 8; ++mi) {
        const int rowb = m0 + wr * 128 + mi * 16 + kg * 4;
#pragma unroll
        for (int r = 0; r < 4; ++r) {
          const size_t idx = (size_t)(rowb + r) * N + col;
          const float p = sigm(acc[mi][ni][r] + b);
          Pout[idx] = f2bf(p);
          const float d = bf2f(inbf[idx]) - p;
          cs += d;
          esum += d * d;
        }
      }
      cs += __shfl_xor(cs, 16);
      cs += __shfl_xor(cs, 32);
      if (kg == 0) atomicAdd(&colsum[col], cs);
    }
    esum += __shfl_xor(esum, 1);
    esum += __shfl_xor(esum, 2);
    esum += __shfl_xor(esum, 4);
    esum += __shfl_xor(esum, 8);
    esum += __shfl_xor(esum, 16);
    esum += __shfl_xor(esum, 32);
    if (lane == 0) ered[wid] = esum;
    __syncthreads();
    if (tid == 0) {
      float s = 0.0f;
#pragma unroll
      for (int w = 0; w < 8; ++w) s += ered[w];
      atomicAdd(err_accum, s);
    }
  }
}

// ---------------- NT GEMM for associations (split-K via z) ----------------
// EOP 0: out = acc;  EOP 1: out -= acc.
template <int EOP>
__global__ __launch_bounds__(512, 2)
void gemm_nt256(const ushort_t* __restrict__ Ab,
                const ushort_t* __restrict__ Bb,
                int Ng, int ld, int ksp, float* __restrict__ outd) {
  extern __shared__ ushort_t Lsh[];
  const int tid = threadIdx.x;
  const int wid = tid >> 6, lane = tid & 63;
  const int wr = wid >> 2, wc = wid & 3;
  const int lr = lane & 15, kg = lane >> 4;

  const int nwg = gridDim.x * gridDim.y;
  const int id = blockIdx.y * gridDim.x + blockIdx.x;
  const int sid = (id & 7) * (nwg >> 3) + (id >> 3);
  const int n0 = (sid % gridDim.x) * 256;
  const int m0 = (sid / gridDim.x) * 256;
  const size_t kb0 = (size_t)blockIdx.z * ksp;

  floatx4 acc[8][4] = {};
  core256(Ab + (size_t)m0 * ld + kb0, Bb + (size_t)n0 * ld + kb0, ld, ld, ksp / 64,
          Lsh, wid, lane, wr, wc, acc);

  float* od = outd + (size_t)blockIdx.z * (size_t)gridDim.y * 256 * Ng;
#pragma unroll
  for (int mi = 0; mi < 8; ++mi) {
    const int rowb = m0 + wr * 128 + mi * 16 + kg * 4;
#pragma unroll
    for (int ni = 0; ni < 4; ++ni) {
      const int col = n0 + wc * 64 + ni * 16 + lr;
#pragma unroll
      for (int r = 0; r < 4; ++r) {
        float* p = &od[(size_t)(rowb + r) * Ng + col];
        if (EOP == 0) *p = acc[mi][ni][r];
        else          *p -= acc[mi][ni][r];
      }
    }
  }
}

// ---------------- weight update (sums 4 split-K slices) ----------------
__global__ void wupdate_kernel(const float* __restrict__ W, const float* __restrict__ wm,
                               const float* __restrict__ diff, float* __restrict__ outW) {
  const int i = blockIdx.x * blockDim.x + threadIdx.x;
  constexpr size_t SL = (size_t)NV * NH / 4;
  const floatx4 w = ((const floatx4*)W)[i];
  const floatx4 m = ((const floatx4*)wm)[i];
  const floatx4 a = ((const floatx4*)diff)[i];
  const floatx4 b = ((const floatx4*)diff)[i + SL];
  const floatx4 c = ((const floatx4*)diff)[i + 2 * SL];
  const floatx4 d = ((const floatx4*)diff)[i + 3 * SL];
  floatx4 o;
#pragma unroll
  for (int j = 0; j < 4; ++j)
    o[j] = (w[j] + (m[j] * MOM + (a[j] + b[j]) + (c[j] + d[j])) * LRB) * (1.0f - WD);
  ((floatx4*)outW)[i] = o;
}

// ---------------- bias updates + error ----------------
__global__ void biaserr_kernel(const float* __restrict__ vb, const float* __restrict__ vbm,
                               const float* __restrict__ vbcs,
                               const float* __restrict__ hb, const float* __restrict__ hbm,
                               const float* __restrict__ phpcs, const float* __restrict__ nhpcs,
                               const float* __restrict__ err, float* __restrict__ out) {
  const int i = blockIdx.x * blockDim.x + threadIdx.x;
  if (i < NV) out[1 + (size_t)NV * NH + i] = vb[i] + (vbm[i] * MOM + vbcs[i]) * LRB;
  if (i < NH) out[1 + (size_t)NV * NH + NV + i] = hb[i] + (hbm[i] * MOM + (phpcs[i] - nhpcs[i])) * LRB;
  if (i == 0) out[0] = err[0];
}

extern "C" void kernel_launch(void* const* d_in, const int* in_sizes, int n_in,
                              void* d_out, int out_size, void* d_ws, size_t ws_size,
                              hipStream_t stream) {
  const float* inputs  = (const float*)d_in[0];
  const float* W       = (const float*)d_in[1];
  const float* vb      = (const float*)d_in[2];
  const float* hb      = (const float*)d_in[3];
  const float* wmom    = (const float*)d_in[4];
  const float* vbmom   = (const float*)d_in[5];
  const float* hbmom   = (const float*)d_in[6];
  const float* rand_h0 = (const float*)d_in[7];

  // allow 128KiB dynamic LDS (idempotent host-side calls, capture-safe)
  hipFuncSetAttribute((const void*)gemm_fused256<0>, hipFuncAttributeMaxDynamicSharedMemorySize, (int)LDS_BYTES);
  hipFuncSetAttribute((const void*)gemm_fused256<1>, hipFuncAttributeMaxDynamicSharedMemorySize, (int)LDS_BYTES);
  hipFuncSetAttribute((const void*)gemm_fused256<2>, hipFuncAttributeMaxDynamicSharedMemorySize, (int)LDS_BYTES);
  hipFuncSetAttribute((const void*)gemm_nt256<0>, hipFuncAttributeMaxDynamicSharedMemorySize, (int)LDS_BYTES);
  hipFuncSetAttribute((const void*)gemm_nt256<1>, hipFuncAttributeMaxDynamicSharedMemorySize, (int)LDS_BYTES);

  char* ws = (char*)d_ws;
  size_t off = 0;
  auto take = [&](size_t b) { size_t r = off; off = (off + b + 1023) & ~(size_t)1023; return r; };
  ushort_t* Wbf   = (ushort_t*)(ws + take((size_t)NV * NH * 2));
  ushort_t* WT    = (ushort_t*)(ws + take((size_t)NV * NH * 2));
  ushort_t* inbf  = (ushort_t*)(ws + take((size_t)NB * NV * 2));  // reused as nvpT
  ushort_t* inT   = (ushort_t*)(ws + take((size_t)NB * NV * 2));
  ushort_t* nvp   = (ushort_t*)(ws + take((size_t)NB * NV * 2));  // reused as diff (64MB < 128MB)
  ushort_t* acts  = (ushort_t*)(ws + take((size_t)NB * NH * 2));  // reused as nhp
  ushort_t* actsT = (ushort_t*)(ws + take((size_t)NB * NH * 2));
  ushort_t* nhpT  = (ushort_t*)(ws + take((size_t)NB * NH * 2));
  const size_t red_bytes = (size_t)(NH + NH + NV + 64) * 4;
  float* phpcs = (float*)(ws + take(red_bytes));
  float* nhpcs = phpcs + NH;
  float* vbcs  = nhpcs + NH;
  float* errp  = vbcs + NV;

  ushort_t* nvpT = inbf;          // overlay: inbf dead after gemm_fused256<1>
  ushort_t* nhp  = acts;          // overlay: acts dead after gemm_fused256<1>
  float* diff    = (float*)nvp;   // overlay: nvp dead after transb + gemm_fused256<2>

  hipMemsetAsync(phpcs, 0, red_bytes, stream);

  // prep: bf16 conversions + transposes of inputs and W
  prep_cvt_t<<<dim3(NV / 64, NB / 64), 256, 0, stream>>>(inputs, inbf, inT, NB, NV);
  prep_cvt_t<<<dim3(NH / 64, NV / 64), 256, 0, stream>>>(W, Wbf, WT, NV, NH);

  // 1) pos hidden: acts = (sigm(inbf @ WT^T + hb) >= rand_h0)
  gemm_fused256<0><<<dim3(NH / 256, NB / 256), 512, LDS_BYTES, stream>>>(
      inbf, WT, NH, NV, hb, rand_h0, acts, phpcs, nullptr, nullptr);
  transb<<<dim3(NH / 64, NB / 64), 256, 0, stream>>>(acts, actsT, NB, NH);

  // 2) neg visible: nvp = sigm(acts @ Wbf^T + vb); fused err + vb colsum
  gemm_fused256<1><<<dim3(NV / 256, NB / 256), 512, LDS_BYTES, stream>>>(
      acts, Wbf, NV, NH, vb, nullptr, nvp, vbcs, inbf, errp);
  transb<<<dim3(NV / 64, NB / 64), 256, 0, stream>>>(nvp, nvpT, NB, NV);

  // 3) neg hidden: nhp = sigm(nvp @ WT^T + hb)
  gemm_fused256<2><<<dim3(NH / 256, NB / 256), 512, LDS_BYTES, stream>>>(
      nvp, WT, NH, NV, hb, nullptr, nhp, nhpcs, nullptr, nullptr);
  transb<<<dim3(NH / 64, NB / 64), 256, 0, stream>>>(nhp, nhpT, NB, NH);

  // 4) diff = inputs^T @ acts - nvp^T @ nhp  (split-K=4 slices, no atomics)
  gemm_nt256<0><<<dim3(NH / 256, NV / 256, 4), 512, LDS_BYTES, stream>>>(
      inT, actsT, NH, NB, NB / 4, diff);
  gemm_nt256<1><<<dim3(NH / 256, NV / 256, 4), 512, LDS_BYTES, stream>>>(
      nvpT, nhpT, NH, NB, NB / 4, diff);

  // 5) parameter updates + error
  wupdate_kernel<<<dim3((NV * NH / 4) / 256), 256, 0, stream>>>(W, wmom, diff, (float*)d_out + 1);
  biaserr_kernel<<<dim3(16), 256, 0, stream>>>(vb, vbmom, vbcs, hb, hbmom, phpcs, nhpcs, errp,
                                               (float*)d_out);
}

// Round 4
// 1151.993 us; speedup vs baseline: 1.1592x; 1.1592x over previous
//
#include <hip/hip_runtime.h>
#include <hip/hip_bf16.h>

#define DEV __device__ __forceinline__

typedef __attribute__((ext_vector_type(8))) short bhalf8;
typedef __attribute__((ext_vector_type(4))) short bhalf4;
typedef __attribute__((ext_vector_type(4))) float floatx4;
typedef unsigned short ushort_t;

constexpr int NB = 16384;   // batch
constexpr int NV = 4096;    // visible
constexpr int NH = 1024;    // hidden
constexpr float MOM = 0.5f;
constexpr float WD  = 1e-4f;
constexpr float LRB = 1e-3f / 16384.0f;

// 256x256 tile, K-panel = 32; 4 LDS slots of 32KB (A 16KB + B 16KB)
constexpr int LDS_SHORTS = 65536;      // 128 KiB
constexpr size_t LDS_BYTES = 131136;   // + 64B epilogue reduction

DEV unsigned short f2bf(float f) {
  unsigned u = __builtin_bit_cast(unsigned, f);
  u += 0x7FFFu + ((u >> 16) & 1u);      // RNE
  return (unsigned short)(u >> 16);
}
DEV float bf2f(unsigned short u) {
  unsigned x = ((unsigned)u) << 16;
  return __builtin_bit_cast(float, x);
}
DEV float sigm(float x) { return 1.0f / (1.0f + __expf(-x)); }

DEV void gl16(const ushort_t* g, ushort_t* l) {
  __builtin_amdgcn_global_load_lds(
      (const __attribute__((address_space(1))) void*)g,
      (__attribute__((address_space(3))) void*)l,
      16, 0, 0);
}

// ---------- f32 [R][C] -> bf16 [R][C] and bf16 [C][R] ----------
__global__ void prep_cvt_t(const float* __restrict__ in,
                           ushort_t* __restrict__ obf,
                           ushort_t* __restrict__ oT, int R, int C) {
  __shared__ ushort_t t[64][72];
  const int c0 = blockIdx.x * 64, r0 = blockIdx.y * 64;
  const int tr = threadIdx.x >> 3, tc = (threadIdx.x & 7) * 8;
#pragma unroll
  for (int s = 0; s < 64; s += 32) {
    const float* p = in + (size_t)(r0 + tr + s) * C + c0 + tc;
    floatx4 lo = *(const floatx4*)p, hi = *(const floatx4*)(p + 4);
    bhalf8 r;
    r[0] = (short)f2bf(lo[0]); r[1] = (short)f2bf(lo[1]);
    r[2] = (short)f2bf(lo[2]); r[3] = (short)f2bf(lo[3]);
    r[4] = (short)f2bf(hi[0]); r[5] = (short)f2bf(hi[1]);
    r[6] = (short)f2bf(hi[2]); r[7] = (short)f2bf(hi[3]);
    *(bhalf8*)(obf + (size_t)(r0 + tr + s) * C + c0 + tc) = r;
    *(bhalf8*)&t[tr + s][tc] = r;
  }
  __syncthreads();
#pragma unroll
  for (int s = 0; s < 64; s += 32) {
    bhalf8 v;
#pragma unroll
    for (int j = 0; j < 8; ++j) v[j] = (short)t[tc + j][tr + s];
    *(bhalf8*)(oT + (size_t)(c0 + tr + s) * R + r0 + tc) = v;
  }
}

// ============ 256x256 panel-pipelined core ============
// A: [M][ldA] bf16 tile base, B: [N][ldB] bf16 tile base. NP = K/32 panels (NP>=3).
// LDS slot s (s=p&3): A panel 256x32 at s*16384, B panel at s*16384+8192.
// Staging 3 panels ahead; counted vmcnt at panel-closing barrier (T3+T4).
DEV void core256(const ushort_t* __restrict__ Ap,
                 const ushort_t* __restrict__ Bp,
                 size_t ldA, size_t ldB, int NP,
                 ushort_t* Lp, int wid, int lane,
                 int wr, int wc, floatx4 (&acc)[8][4]) {
  const int lr = lane & 15, kg = lane >> 4;
  const int srow = wid * 16 + (lane >> 2);
  const int scol = (lane & 3) * 8;
  const ushort_t* gA = Ap + (size_t)srow * ldA + scol;
  const ushort_t* gB = Bp + (size_t)srow * ldB + scol;
  ushort_t* dA = Lp + wid * 512;
  ushort_t* dB = Lp + 8192 + wid * 512;
  const ushort_t* aB = Lp + (wr * 128 + lr) * 32 + kg * 8;
  const ushort_t* bB = Lp + 8192 + (wc * 64 + lr) * 32 + kg * 8;

  auto stage = [&](int p) {      // 4 gl16 per wave (A:2, B:2), 32KB per block
    const int slot = (p & 3) * 16384;
    const size_t kb = (size_t)p * 32;
#pragma unroll
    for (int i = 0; i < 2; ++i) {
      gl16(gA + (size_t)(i * 128) * ldA + kb, dA + slot + i * 4096);
      gl16(gB + (size_t)(i * 128) * ldB + kb, dB + slot + i * 4096);
    }
  };

  stage(0); stage(1); stage(2);
  asm volatile("s_waitcnt vmcnt(8)" ::: "memory");   // panel 0 resident
  asm volatile("s_barrier" ::: "memory");

  for (int p = 0; p < NP; ++p) {
    const int slot = (p & 3) * 16384;
    bhalf8 fa[4], fb[4], fa2[4];
    // ---- phase (p, mh0): 8 ds_read + stage(p+3) + 16 MFMA ----
#pragma unroll
    for (int i = 0; i < 4; ++i) fa[i] = *(const bhalf8*)(aB + slot + i * 512);
#pragma unroll
    for (int i = 0; i < 4; ++i) fb[i] = *(const bhalf8*)(bB + slot + i * 512);
    if (p + 3 < NP) stage(p + 3);
    asm volatile("s_barrier" ::: "memory");
    asm volatile("s_waitcnt lgkmcnt(0)" ::: "memory");
    __builtin_amdgcn_sched_barrier(0);
    __builtin_amdgcn_s_setprio(1);
#pragma unroll
    for (int m2 = 0; m2 < 4; ++m2)
#pragma unroll
      for (int n = 0; n < 4; ++n)
        acc[m2][n] = __builtin_amdgcn_mfma_f32_16x16x32_bf16(fa[m2], fb[n], acc[m2][n], 0, 0, 0);
    __builtin_amdgcn_s_setprio(0);
    asm volatile("s_barrier" ::: "memory");
    // ---- phase (p, mh1): 4 ds_read (fb reused) + 16 MFMA ----
#pragma unroll
    for (int i = 0; i < 4; ++i) fa2[i] = *(const bhalf8*)(aB + slot + 2048 + i * 512);
    asm volatile("s_barrier" ::: "memory");
    asm volatile("s_waitcnt lgkmcnt(0)" ::: "memory");
    __builtin_amdgcn_sched_barrier(0);
    __builtin_amdgcn_s_setprio(1);
#pragma unroll
    for (int m2 = 0; m2 < 4; ++m2)
#pragma unroll
      for (int n = 0; n < 4; ++n)
        acc[4 + m2][n] = __builtin_amdgcn_mfma_f32_16x16x32_bf16(fa2[m2], fb[n], acc[4 + m2][n], 0, 0, 0);
    __builtin_amdgcn_s_setprio(0);
    // counted wait: validate panel p+1 for the next iteration's ds_reads
    if (p + 3 < NP)      asm volatile("s_waitcnt vmcnt(8)" ::: "memory");
    else if (p + 2 < NP) asm volatile("s_waitcnt vmcnt(4)" ::: "memory");
    else if (p + 1 < NP) asm volatile("s_waitcnt vmcnt(0)" ::: "memory");
    asm volatile("s_barrier" ::: "memory");
  }
}

// ---------------- fused NT GEMM: sigmoid(A @ B^T + bias) + epilogues ----------------
// MODE 0: Pout=acts(0/1) + PoutT, colsum += p
// MODE 1: Pout=p + PoutT, colsum += (in-p), err += (in-p)^2
// MODE 2: PoutT only, colsum += p
template <int MODE>
__global__ __launch_bounds__(512, 2)
void gemm_fused256(const ushort_t* __restrict__ Ab,
                   const ushort_t* __restrict__ Bb,
                   int N, int K,
                   const float* __restrict__ bias,
                   const float* __restrict__ rand_h0,
                   ushort_t* __restrict__ Pout,
                   ushort_t* __restrict__ PoutT,
                   float* __restrict__ colsum,
                   const ushort_t* __restrict__ inbf,
                   float* __restrict__ err_accum) {
  extern __shared__ ushort_t Lsh[];
  const int tid = threadIdx.x;
  const int wid = tid >> 6, lane = tid & 63;
  const int wr = wid >> 2, wc = wid & 3;
  const int lr = lane & 15, kg = lane >> 4;

  const int nwg = gridDim.x * gridDim.y;
  const int id = blockIdx.y * gridDim.x + blockIdx.x;
  const int sid = (id & 7) * (nwg >> 3) + (id >> 3);
  const int n0 = (sid % gridDim.x) * 256;
  const int m0 = (sid / gridDim.x) * 256;

  floatx4 acc[8][4] = {};
  core256(Ab + (size_t)m0 * K, Bb + (size_t)n0 * K, K, K, K / 32,
          Lsh, wid, lane, wr, wc, acc);

  float esum = 0.0f;
#pragma unroll
  for (int ni = 0; ni < 4; ++ni) {
    const int col = n0 + wc * 64 + ni * 16 + lr;
    const float b = bias[col];
    const float r0 = (MODE == 0) ? rand_h0[col] : 0.0f;
    float cs = 0.0f;
#pragma unroll
    for (int mi = 0; mi < 8; ++mi) {
      const int rowb = m0 + wr * 128 + mi * 16 + kg * 4;
      bhalf4 tp;
#pragma unroll
      for (int r = 0; r < 4; ++r) {
        const float p = sigm(acc[mi][ni][r] + b);
        ushort_t ov;
        if (MODE == 0) {
          cs += p;
          ov = (p >= r0) ? (ushort_t)0x3F80u : (ushort_t)0u;
          Pout[(size_t)(rowb + r) * N + col] = ov;
        } else if (MODE == 1) {
          ov = f2bf(p);
          Pout[(size_t)(rowb + r) * N + col] = ov;
          const float d = bf2f(inbf[(size_t)(rowb + r) * N + col]) - p;
          cs += d;
          esum += d * d;
        } else {
          cs += p;
          ov = f2bf(p);
        }
        tp[r] = (short)ov;
      }
      *(bhalf4*)&PoutT[(size_t)col * NB + rowb] = tp;   // transposed write (8B/lane)
    }
    cs += __shfl_xor(cs, 16);
    cs += __shfl_xor(cs, 32);
    if (kg == 0) atomicAdd(&colsum[col], cs);
  }
  if (MODE == 1) {
    float* ered = (float*)(Lsh + LDS_SHORTS);
    esum += __shfl_xor(esum, 1);
    esum += __shfl_xor(esum, 2);
    esum += __shfl_xor(esum, 4);
    esum += __shfl_xor(esum, 8);
    esum += __shfl_xor(esum, 16);
    esum += __shfl_xor(esum, 32);
    if (lane == 0) ered[wid] = esum;
    __syncthreads();
    if (tid == 0) {
      float s = 0.0f;
#pragma unroll
      for (int w = 0; w < 8; ++w) s += ered[w];
      atomicAdd(err_accum, s);
    }
  }
}

// ---------------- NT GEMM for associations (split-K via z, slice outputs) ----------------
// EOP 0: out = acc;  EOP 1: out -= acc.
template <int EOP>
__global__ __launch_bounds__(512, 2)
void gemm_nt256(const ushort_t* __restrict__ Ab,
                const ushort_t* __restrict__ Bb,
                int Ng, int ld, int ksp, float* __restrict__ outd) {
  extern __shared__ ushort_t Lsh[];
  const int tid = threadIdx.x;
  const int wid = tid >> 6, lane = tid & 63;
  const int wr = wid >> 2, wc = wid & 3;
  const int lr = lane & 15, kg = lane >> 4;

  const int nwg = gridDim.x * gridDim.y;
  const int id = blockIdx.y * gridDim.x + blockIdx.x;
  const int sid = (id & 7) * (nwg >> 3) + (id >> 3);
  const int n0 = (sid % gridDim.x) * 256;
  const int m0 = (sid / gridDim.x) * 256;
  const size_t kb0 = (size_t)blockIdx.z * ksp;

  floatx4 acc[8][4] = {};
  core256(Ab + (size_t)m0 * ld + kb0, Bb + (size_t)n0 * ld + kb0, ld, ld, ksp / 32,
          Lsh, wid, lane, wr, wc, acc);

  float* od = outd + (size_t)blockIdx.z * (size_t)gridDim.y * 256 * Ng;
#pragma unroll
  for (int mi = 0; mi < 8; ++mi) {
    const int rowb = m0 + wr * 128 + mi * 16 + kg * 4;
#pragma unroll
    for (int ni = 0; ni < 4; ++ni) {
      const int col = n0 + wc * 64 + ni * 16 + lr;
#pragma unroll
      for (int r = 0; r < 4; ++r) {
        float* p = &od[(size_t)(rowb + r) * Ng + col];
        if (EOP == 0) *p = acc[mi][ni][r];
        else          *p -= acc[mi][ni][r];
      }
    }
  }
}

// ---------------- weight update (sums 4 split-K slices) ----------------
__global__ void wupdate_kernel(const float* __restrict__ W, const float* __restrict__ wm,
                               const float* __restrict__ diff, float* __restrict__ outW) {
  const int i = blockIdx.x * blockDim.x + threadIdx.x;
  constexpr size_t SL = (size_t)NV * NH / 4;
  const floatx4 w = ((const floatx4*)W)[i];
  const floatx4 m = ((const floatx4*)wm)[i];
  const floatx4 a = ((const floatx4*)diff)[i];
  const floatx4 b = ((const floatx4*)diff)[i + SL];
  const floatx4 c = ((const floatx4*)diff)[i + 2 * SL];
  const floatx4 d = ((const floatx4*)diff)[i + 3 * SL];
  floatx4 o;
#pragma unroll
  for (int j = 0; j < 4; ++j)
    o[j] = (w[j] + (m[j] * MOM + (a[j] + b[j]) + (c[j] + d[j])) * LRB) * (1.0f - WD);
  ((floatx4*)outW)[i] = o;
}

// ---------------- bias updates + error ----------------
__global__ void biaserr_kernel(const float* __restrict__ vb, const float* __restrict__ vbm,
                               const float* __restrict__ vbcs,
                               const float* __restrict__ hb, const float* __restrict__ hbm,
                               const float* __restrict__ phpcs, const float* __restrict__ nhpcs,
                               const float* __restrict__ err, float* __restrict__ out) {
  const int i = blockIdx.x * blockDim.x + threadIdx.x;
  if (i < NV) out[1 + (size_t)NV * NH + i] = vb[i] + (vbm[i] * MOM + vbcs[i]) * LRB;
  if (i < NH) out[1 + (size_t)NV * NH + NV + i] = hb[i] + (hbm[i] * MOM + (phpcs[i] - nhpcs[i])) * LRB;
  if (i == 0) out[0] = err[0];
}

extern "C" void kernel_launch(void* const* d_in, const int* in_sizes, int n_in,
                              void* d_out, int out_size, void* d_ws, size_t ws_size,
                              hipStream_t stream) {
  const float* inputs  = (const float*)d_in[0];
  const float* W       = (const float*)d_in[1];
  const float* vb      = (const float*)d_in[2];
  const float* hb      = (const float*)d_in[3];
  const float* wmom    = (const float*)d_in[4];
  const float* vbmom   = (const float*)d_in[5];
  const float* hbmom   = (const float*)d_in[6];
  const float* rand_h0 = (const float*)d_in[7];

  hipFuncSetAttribute((const void*)gemm_fused256<0>, hipFuncAttributeMaxDynamicSharedMemorySize, (int)LDS_BYTES);
  hipFuncSetAttribute((const void*)gemm_fused256<1>, hipFuncAttributeMaxDynamicSharedMemorySize, (int)LDS_BYTES);
  hipFuncSetAttribute((const void*)gemm_fused256<2>, hipFuncAttributeMaxDynamicSharedMemorySize, (int)LDS_BYTES);
  hipFuncSetAttribute((const void*)gemm_nt256<0>, hipFuncAttributeMaxDynamicSharedMemorySize, (int)LDS_BYTES);
  hipFuncSetAttribute((const void*)gemm_nt256<1>, hipFuncAttributeMaxDynamicSharedMemorySize, (int)LDS_BYTES);

  char* ws = (char*)d_ws;
  size_t off = 0;
  auto take = [&](size_t b) { size_t r = off; off = (off + b + 1023) & ~(size_t)1023; return r; };
  ushort_t* Wbf   = (ushort_t*)(ws + take((size_t)NV * NH * 2));
  ushort_t* WT    = (ushort_t*)(ws + take((size_t)NV * NH * 2));
  ushort_t* inbf  = (ushort_t*)(ws + take((size_t)NB * NV * 2));  // reused as diff slices
  ushort_t* inT   = (ushort_t*)(ws + take((size_t)NB * NV * 2));
  ushort_t* nvp   = (ushort_t*)(ws + take((size_t)NB * NV * 2));
  ushort_t* nvpT  = (ushort_t*)(ws + take((size_t)NB * NV * 2));  // own buffer (no alias w/ inbf!)
  ushort_t* acts  = (ushort_t*)(ws + take((size_t)NB * NH * 2));
  ushort_t* actsT = (ushort_t*)(ws + take((size_t)NB * NH * 2));
  ushort_t* nhpT  = (ushort_t*)(ws + take((size_t)NB * NH * 2));
  const size_t red_bytes = (size_t)(NH + NH + NV + 64) * 4;
  float* phpcs = (float*)(ws + take(red_bytes));
  float* nhpcs = phpcs + NH;
  float* vbcs  = nhpcs + NH;
  float* errp  = vbcs + NV;

  float* diff = (float*)inbf;   // overlay: inbf dead after gemm_fused256<1> (64MB <= 128MB)

  hipMemsetAsync(phpcs, 0, red_bytes, stream);

  // prep: bf16 conversions + transposes of inputs and W
  prep_cvt_t<<<dim3(NV / 64, NB / 64), 256, 0, stream>>>(inputs, inbf, inT, NB, NV);
  prep_cvt_t<<<dim3(NH / 64, NV / 64), 256, 0, stream>>>(W, Wbf, WT, NV, NH);

  // 1) pos hidden: acts/actsT = (sigm(inbf @ WT^T + hb) >= rand_h0)
  gemm_fused256<0><<<dim3(NH / 256, NB / 256), 512, LDS_BYTES, stream>>>(
      inbf, WT, NH, NV, hb, rand_h0, acts, actsT, phpcs, nullptr, nullptr);

  // 2) neg visible: nvp/nvpT = sigm(acts @ Wbf^T + vb); fused err + vb colsum
  gemm_fused256<1><<<dim3(NV / 256, NB / 256), 512, LDS_BYTES, stream>>>(
      acts, Wbf, NV, NH, vb, nullptr, nvp, nvpT, vbcs, inbf, errp);

  // 3) neg hidden: nhpT = sigm(nvp @ WT^T + hb)   (transposed only)
  gemm_fused256<2><<<dim3(NH / 256, NB / 256), 512, LDS_BYTES, stream>>>(
      nvp, WT, NH, NV, hb, nullptr, nullptr, nhpT, nhpcs, nullptr, nullptr);

  // 4) diff = inputs^T @ acts - nvp^T @ nhp  (split-K=4 slices, no atomics)
  gemm_nt256<0><<<dim3(NH / 256, NV / 256, 4), 512, LDS_BYTES, stream>>>(
      inT, actsT, NH, NB, NB / 4, diff);
  gemm_nt256<1><<<dim3(NH / 256, NV / 256, 4), 512, LDS_BYTES, stream>>>(
      nvpT, nhpT, NH, NB, NB / 4, diff);

  // 5) parameter updates + error
  wupdate_kernel<<<dim3((NV * NH / 4) / 256), 256, 0, stream>>>(W, wmom, diff, (float*)d_out + 1);
  biaserr_kernel<<<dim3(16), 256, 0, stream>>>(vb, vbmom, vbcs, hb, hbmom, phpcs, nhpcs, errp,
                                               (float*)d_out);
}

// Round 5
// 1143.216 us; speedup vs baseline: 1.1681x; 1.0077x over previous
//
#include <hip/hip_runtime.h>
#include <hip/hip_bf16.h>

#define DEV __device__ __forceinline__

typedef __attribute__((ext_vector_type(8))) short bhalf8;
typedef __attribute__((ext_vector_type(4))) short bhalf4;
typedef __attribute__((ext_vector_type(4))) float floatx4;
typedef unsigned short ushort_t;

constexpr int NB = 16384;   // batch
constexpr int NV = 4096;    // visible
constexpr int NH = 1024;    // hidden
constexpr float MOM = 0.5f;
constexpr float WD  = 1e-4f;
constexpr float LRB = 1e-3f / 16384.0f;

// Tile 256(M) x 128(N) x 32(K); 4 waves, each owns 128x64 (8x4 fragments).
// 3 LDS buffers of 24KB (A 16KB + B 8KB) = 72KB -> 2 blocks/CU.
constexpr int BUF_SHORTS = 12288;            // per buffer
constexpr int LDS_SHORTS = 3 * BUF_SHORTS;   // 36864 shorts = 72KB
constexpr size_t LDS_BYTES = LDS_SHORTS * 2 + 64;

DEV unsigned short f2bf(float f) {
  unsigned u = __builtin_bit_cast(unsigned, f);
  u += 0x7FFFu + ((u >> 16) & 1u);      // RNE
  return (unsigned short)(u >> 16);
}
DEV float bf2f(unsigned short u) {
  unsigned x = ((unsigned)u) << 16;
  return __builtin_bit_cast(float, x);
}
DEV float sigm(float x) { return 1.0f / (1.0f + __expf(-x)); }

DEV void gl16(const ushort_t* g, ushort_t* l) {
  __builtin_amdgcn_global_load_lds(
      (const __attribute__((address_space(1))) void*)g,
      (__attribute__((address_space(3))) void*)l,
      16, 0, 0);
}

// ---------- f32 [R][C] -> bf16 [R][C] and bf16 [C][R] ----------
__global__ void prep_cvt_t(const float* __restrict__ in,
                           ushort_t* __restrict__ obf,
                           ushort_t* __restrict__ oT, int R, int C) {
  __shared__ ushort_t t[64][72];
  const int c0 = blockIdx.x * 64, r0 = blockIdx.y * 64;
  const int tr = threadIdx.x >> 3, tc = (threadIdx.x & 7) * 8;
#pragma unroll
  for (int s = 0; s < 64; s += 32) {
    const float* p = in + (size_t)(r0 + tr + s) * C + c0 + tc;
    floatx4 lo = *(const floatx4*)p, hi = *(const floatx4*)(p + 4);
    bhalf8 r;
    r[0] = (short)f2bf(lo[0]); r[1] = (short)f2bf(lo[1]);
    r[2] = (short)f2bf(lo[2]); r[3] = (short)f2bf(lo[3]);
    r[4] = (short)f2bf(hi[0]); r[5] = (short)f2bf(hi[1]);
    r[6] = (short)f2bf(hi[2]); r[7] = (short)f2bf(hi[3]);
    *(bhalf8*)(obf + (size_t)(r0 + tr + s) * C + c0 + tc) = r;
    *(bhalf8*)&t[tr + s][tc] = r;
  }
  __syncthreads();
#pragma unroll
  for (int s = 0; s < 64; s += 32) {
    bhalf8 v;
#pragma unroll
    for (int j = 0; j < 8; ++j) v[j] = (short)t[tc + j][tr + s];
    *(bhalf8*)(oT + (size_t)(c0 + tr + s) * R + r0 + tc) = v;
  }
}

// ============ 256x128x32 core: 3-buf, stage-depth-2, counted vmcnt ============
// A: [256 rows][ldA] bf16 tile base, B: [128 rows][ldB] bf16 tile base.
// LDS buf b at Lp + b*12288: A 256x32 (8192 shorts), B 128x32 at +8192.
// Swizzle: 16B slot index ^= ((row&8)?2:0)|((row&2)?1:0)  (2-way max on reads).
DEV void core(const ushort_t* __restrict__ Ap,
              const ushort_t* __restrict__ Bp,
              size_t ldA, size_t ldB, int nt,
              ushort_t* Lp, int wid, int lane, int wm, int wn,
              floatx4 (&acc)[8][4]) {
  const int lr = lane & 15, kg = lane >> 4;
  // staging: row within 16-row chunk = lane>>2; source col slot pre-swizzled
  const int sslot = ((lane & 3) ^ (((lane & 32) ? 2 : 0) | ((lane & 8) ? 1 : 0))) * 8;
  const ushort_t* gA = Ap + (size_t)(wid * 16 + (lane >> 2)) * ldA + sslot;
  const ushort_t* gB = Bp + (size_t)(wid * 16 + (lane >> 2)) * ldB + sslot;
  // read-side swizzle (fragment row = ... + lr, so row&8=lr&8, row&2=lr&2)
  const int rslot = ((kg ^ (((lr & 8) ? 2 : 0) | ((lr & 2) ? 1 : 0))) * 8);
  const int aoff = (wm * 128 + lr) * 32 + rslot;
  const int boff = 8192 + (wn * 64 + lr) * 32 + rslot;

  auto stage = [&](int buf, int t) {   // 6 gl16 per wave
    const ushort_t* a = gA + (size_t)t * 32;
    const ushort_t* b = gB + (size_t)t * 32;
    ushort_t* LA = Lp + buf * BUF_SHORTS + wid * 512;
    ushort_t* LB = LA + 8192;
#pragma unroll
    for (int i = 0; i < 4; ++i) gl16(a + (size_t)(i * 64) * ldA, LA + i * 2048);
#pragma unroll
    for (int i = 0; i < 2; ++i) gl16(b + (size_t)(i * 64) * ldB, LB + i * 2048);
  };

  stage(0, 0);
  stage(1, 1);
  int cur = 0, pre = 2;
  for (int t = 0; t < nt; ++t) {
    if (t + 1 < nt) asm volatile("s_waitcnt vmcnt(6)" ::: "memory");
    else            asm volatile("s_waitcnt vmcnt(0)" ::: "memory");
    asm volatile("s_barrier" ::: "memory");
    if (t + 2 < nt) stage(pre, t + 2);         // loads stay in flight across barriers
    const ushort_t* aB = Lp + cur * BUF_SHORTS + aoff;
    const ushort_t* bB = Lp + cur * BUF_SHORTS + boff;
    bhalf8 fa[8], fb[4];
#pragma unroll
    for (int m = 0; m < 8; ++m) fa[m] = *(const bhalf8*)(aB + m * 512);
#pragma unroll
    for (int n = 0; n < 4; ++n) fb[n] = *(const bhalf8*)(bB + n * 512);
    asm volatile("s_waitcnt lgkmcnt(0)" ::: "memory");
    __builtin_amdgcn_sched_barrier(0);
    __builtin_amdgcn_s_setprio(1);
#pragma unroll
    for (int m = 0; m < 8; ++m)
#pragma unroll
      for (int n = 0; n < 4; ++n)
        acc[m][n] = __builtin_amdgcn_mfma_f32_16x16x32_bf16(fa[m], fb[n], acc[m][n], 0, 0, 0);
    __builtin_amdgcn_s_setprio(0);
    if (++cur == 3) cur = 0;
    if (++pre == 3) pre = 0;
  }
}

// ---------------- fused NT GEMM: sigmoid(A @ B^T + bias) + epilogues ----------------
// MODE 0: Pout=acts(0/1) + PoutT, colsum += p
// MODE 1: Pout=p + PoutT, colsum += (in-p), err += (in-p)^2
// MODE 2: PoutT only, colsum += p
template <int MODE>
__global__ __launch_bounds__(256, 2)
void gemm_fused256(const ushort_t* __restrict__ Ab,
                   const ushort_t* __restrict__ Bb,
                   int N, int K,
                   const float* __restrict__ bias,
                   const float* __restrict__ rand_h0,
                   ushort_t* __restrict__ Pout,
                   ushort_t* __restrict__ PoutT,
                   float* __restrict__ colsum,
                   const ushort_t* __restrict__ inbf,
                   float* __restrict__ err_accum) {
  extern __shared__ ushort_t Lsh[];
  const int tid = threadIdx.x;
  const int wid = tid >> 6, lane = tid & 63;
  const int wm = wid >> 1, wn = wid & 1;
  const int lr = lane & 15, kg = lane >> 4;

  const int nwg = gridDim.x * gridDim.y;
  const int id = blockIdx.y * gridDim.x + blockIdx.x;
  const int sid = (id & 7) * (nwg >> 3) + (id >> 3);   // bijective (nwg%8==0)
  const int n0 = (sid % gridDim.x) * 128;
  const int m0 = (sid / gridDim.x) * 256;

  floatx4 acc[8][4] = {};
  core(Ab + (size_t)m0 * K, Bb + (size_t)n0 * K, K, K, K / 32,
       Lsh, wid, lane, wm, wn, acc);

  float esum = 0.0f;
#pragma unroll
  for (int ni = 0; ni < 4; ++ni) {
    const int col = n0 + wn * 64 + ni * 16 + lr;
    const float b = bias[col];
    const float r0 = (MODE == 0) ? rand_h0[col] : 0.0f;
    float cs = 0.0f;
#pragma unroll
    for (int mi = 0; mi < 8; ++mi) {
      const int rowb = m0 + wm * 128 + mi * 16 + kg * 4;
      bhalf4 tp;
#pragma unroll
      for (int r = 0; r < 4; ++r) {
        const float p = sigm(acc[mi][ni][r] + b);
        ushort_t ov;
        if (MODE == 0) {
          cs += p;
          ov = (p >= r0) ? (ushort_t)0x3F80u : (ushort_t)0u;
          Pout[(size_t)(rowb + r) * N + col] = ov;
        } else if (MODE == 1) {
          ov = f2bf(p);
          Pout[(size_t)(rowb + r) * N + col] = ov;
          const float d = bf2f(inbf[(size_t)(rowb + r) * N + col]) - p;
          cs += d;
          esum += d * d;
        } else {
          cs += p;
          ov = f2bf(p);
        }
        tp[r] = (short)ov;
      }
      *(bhalf4*)&PoutT[(size_t)col * NB + rowb] = tp;   // transposed write
    }
    cs += __shfl_xor(cs, 16);
    cs += __shfl_xor(cs, 32);
    if (kg == 0) atomicAdd(&colsum[col], cs);
  }
  if (MODE == 1) {
    float* ered = (float*)(Lsh + LDS_SHORTS);
    esum += __shfl_xor(esum, 1);
    esum += __shfl_xor(esum, 2);
    esum += __shfl_xor(esum, 4);
    esum += __shfl_xor(esum, 8);
    esum += __shfl_xor(esum, 16);
    esum += __shfl_xor(esum, 32);
    __syncthreads();
    if (lane == 0) ered[wid] = esum;
    __syncthreads();
    if (tid == 0) atomicAdd(err_accum, ered[0] + ered[1] + ered[2] + ered[3]);
  }
}

// ---------------- dual NT GEMM: out = A1@B1^T - A2@B2^T (split-K via slices) ----------------
// Block mapping keeps blocks sharing an A-panel on one XCD: m_idx = r%16 (XCD = r%8).
__global__ __launch_bounds__(256, 2)
void gemm_nt_dual(const ushort_t* __restrict__ A1, const ushort_t* __restrict__ B1,
                  const ushort_t* __restrict__ A2, const ushort_t* __restrict__ B2,
                  float* __restrict__ outd) {
  extern __shared__ ushort_t Lsh[];
  const int tid = threadIdx.x;
  const int wid = tid >> 6, lane = tid & 63;
  const int wm = wid >> 1, wn = wid & 1;
  const int lr = lane & 15, kg = lane >> 4;

  const int bid = blockIdx.x;
  const int r = bid & 127;
  const int m0 = (r & 15) * 256;        // 16 m-tiles (m%8 == XCD)
  const int n0 = (r >> 4) * 128;        // 8 n-tiles
  const int z  = bid >> 7;              // 4 K-splits
  const size_t kb0 = (size_t)z * (NB / 4);
  constexpr int NT = (NB / 4) / 32;     // 128 panels per pass

  floatx4 acc[8][4] = {};
  core(A1 + (size_t)m0 * NB + kb0, B1 + (size_t)n0 * NB + kb0, NB, NB, NT,
       Lsh, wid, lane, wm, wn, acc);
#pragma unroll
  for (int m = 0; m < 8; ++m)
#pragma unroll
    for (int n = 0; n < 4; ++n)
#pragma unroll
      for (int j = 0; j < 4; ++j) acc[m][n][j] = -acc[m][n][j];
  core(A2 + (size_t)m0 * NB + kb0, B2 + (size_t)n0 * NB + kb0, NB, NB, NT,
       Lsh, wid, lane, wm, wn, acc);
  // acc = P2 - P1  ->  write P1 - P2 = -acc
  float* od = outd + (size_t)z * NV * NH;
#pragma unroll
  for (int mi = 0; mi < 8; ++mi) {
    const int rowb = m0 + wm * 128 + mi * 16 + kg * 4;
#pragma unroll
    for (int ni = 0; ni < 4; ++ni) {
      const int col = n0 + wn * 64 + ni * 16 + lr;
#pragma unroll
      for (int r2 = 0; r2 < 4; ++r2)
        od[(size_t)(rowb + r2) * NH + col] = -acc[mi][ni][r2];
    }
  }
}

// ---------------- weight update (sums 4 split-K slices) ----------------
__global__ void wupdate_kernel(const float* __restrict__ W, const float* __restrict__ wm,
                               const float* __restrict__ diff, float* __restrict__ outW) {
  const int i = blockIdx.x * blockDim.x + threadIdx.x;
  constexpr size_t SL = (size_t)NV * NH / 4;
  const floatx4 w = ((const floatx4*)W)[i];
  const floatx4 m = ((const floatx4*)wm)[i];
  const floatx4 a = ((const floatx4*)diff)[i];
  const floatx4 b = ((const floatx4*)diff)[i + SL];
  const floatx4 c = ((const floatx4*)diff)[i + 2 * SL];
  const floatx4 d = ((const floatx4*)diff)[i + 3 * SL];
  floatx4 o;
#pragma unroll
  for (int j = 0; j < 4; ++j)
    o[j] = (w[j] + (m[j] * MOM + (a[j] + b[j]) + (c[j] + d[j])) * LRB) * (1.0f - WD);
  ((floatx4*)outW)[i] = o;
}

// ---------------- bias updates + error ----------------
__global__ void biaserr_kernel(const float* __restrict__ vb, const float* __restrict__ vbm,
                               const float* __restrict__ vbcs,
                               const float* __restrict__ hb, const float* __restrict__ hbm,
                               const float* __restrict__ phpcs, const float* __restrict__ nhpcs,
                               const float* __restrict__ err, float* __restrict__ out) {
  const int i = blockIdx.x * blockDim.x + threadIdx.x;
  if (i < NV) out[1 + (size_t)NV * NH + i] = vb[i] + (vbm[i] * MOM + vbcs[i]) * LRB;
  if (i < NH) out[1 + (size_t)NV * NH + NV + i] = hb[i] + (hbm[i] * MOM + (phpcs[i] - nhpcs[i])) * LRB;
  if (i == 0) out[0] = err[0];
}

extern "C" void kernel_launch(void* const* d_in, const int* in_sizes, int n_in,
                              void* d_out, int out_size, void* d_ws, size_t ws_size,
                              hipStream_t stream) {
  const float* inputs  = (const float*)d_in[0];
  const float* W       = (const float*)d_in[1];
  const float* vb      = (const float*)d_in[2];
  const float* hb      = (const float*)d_in[3];
  const float* wmom    = (const float*)d_in[4];
  const float* vbmom   = (const float*)d_in[5];
  const float* hbmom   = (const float*)d_in[6];
  const float* rand_h0 = (const float*)d_in[7];

  hipFuncSetAttribute((const void*)gemm_fused256<0>, hipFuncAttributeMaxDynamicSharedMemorySize, (int)LDS_BYTES);
  hipFuncSetAttribute((const void*)gemm_fused256<1>, hipFuncAttributeMaxDynamicSharedMemorySize, (int)LDS_BYTES);
  hipFuncSetAttribute((const void*)gemm_fused256<2>, hipFuncAttributeMaxDynamicSharedMemorySize, (int)LDS_BYTES);
  hipFuncSetAttribute((const void*)gemm_nt_dual, hipFuncAttributeMaxDynamicSharedMemorySize, (int)LDS_BYTES);

  char* ws = (char*)d_ws;
  size_t off = 0;
  auto take = [&](size_t b) { size_t r = off; off = (off + b + 1023) & ~(size_t)1023; return r; };
  ushort_t* Wbf   = (ushort_t*)(ws + take((size_t)NV * NH * 2));
  ushort_t* WT    = (ushort_t*)(ws + take((size_t)NV * NH * 2));
  ushort_t* inbf  = (ushort_t*)(ws + take((size_t)NB * NV * 2));  // reused as diff slices
  ushort_t* inT   = (ushort_t*)(ws + take((size_t)NB * NV * 2));
  ushort_t* nvp   = (ushort_t*)(ws + take((size_t)NB * NV * 2));
  ushort_t* nvpT  = (ushort_t*)(ws + take((size_t)NB * NV * 2));
  ushort_t* acts  = (ushort_t*)(ws + take((size_t)NB * NH * 2));
  ushort_t* actsT = (ushort_t*)(ws + take((size_t)NB * NH * 2));
  ushort_t* nhpT  = (ushort_t*)(ws + take((size_t)NB * NH * 2));
  const size_t red_bytes = (size_t)(NH + NH + NV + 64) * 4;
  float* phpcs = (float*)(ws + take(red_bytes));
  float* nhpcs = phpcs + NH;
  float* vbcs  = nhpcs + NH;
  float* errp  = vbcs + NV;

  float* diff = (float*)inbf;   // overlay: inbf dead after gemm_fused256<1> epilogue

  hipMemsetAsync(phpcs, 0, red_bytes, stream);

  // prep: bf16 conversions + transposes of inputs and W
  prep_cvt_t<<<dim3(NV / 64, NB / 64), 256, 0, stream>>>(inputs, inbf, inT, NB, NV);
  prep_cvt_t<<<dim3(NH / 64, NV / 64), 256, 0, stream>>>(W, Wbf, WT, NV, NH);

  // 1) pos hidden: acts/actsT = (sigm(inbf @ WT^T + hb) >= rand_h0)
  gemm_fused256<0><<<dim3(NH / 128, NB / 256), 256, LDS_BYTES, stream>>>(
      inbf, WT, NH, NV, hb, rand_h0, acts, actsT, phpcs, nullptr, nullptr);

  // 2) neg visible: nvp/nvpT = sigm(acts @ Wbf^T + vb); fused err + vb colsum
  gemm_fused256<1><<<dim3(NV / 128, NB / 256), 256, LDS_BYTES, stream>>>(
      acts, Wbf, NV, NH, vb, nullptr, nvp, nvpT, vbcs, inbf, errp);

  // 3) neg hidden: nhpT = sigm(nvp @ WT^T + hb)
  gemm_fused256<2><<<dim3(NH / 128, NB / 256), 256, LDS_BYTES, stream>>>(
      nvp, WT, NH, NV, hb, nullptr, nullptr, nhpT, nhpcs, nullptr, nullptr);

  // 4) diff slices = inputs^T @ acts - nvp^T @ nhp  (dual-pass, split-K=4)
  gemm_nt_dual<<<dim3(512), 256, LDS_BYTES, stream>>>(inT, actsT, nvpT, nhpT, diff);

  // 5) parameter updates + error
  wupdate_kernel<<<dim3((NV * NH / 4) / 256), 256, 0, stream>>>(W, wmom, diff, (float*)d_out + 1);
  biaserr_kernel<<<dim3(16), 256, 0, stream>>>(vb, vbmom, vbcs, hb, hbmom, phpcs, nhpcs, errp,
                                               (float*)d_out);
}